// Round 1
// baseline (159.078 us; speedup 1.0000x reference)
//
#include <hip/hip_runtime.h>
#include <hip/hip_bf16.h>

#define NROWS 4096
#define TWO_N 8192
#define DDIM 64
#define INV_T 20.0f

typedef short bf16x8 __attribute__((ext_vector_type(8)));
typedef float f32x4 __attribute__((ext_vector_type(4)));

// ---- kernel 1: convert f1|f2 (f32) -> feats bf16 [8192][64], RNE ----
__global__ void convert_kernel(const float* __restrict__ f1,
                               const float* __restrict__ f2,
                               unsigned short* __restrict__ featsb) {
    int idx = blockIdx.x * blockDim.x + threadIdx.x;   // one float4 per thread
    int j = idx * 4;                                    // flat element index
    const int HALF = NROWS * DDIM;                      // 262144
    const float4* src = (j < HALF)
        ? reinterpret_cast<const float4*>(&f1[j])
        : reinterpret_cast<const float4*>(&f2[j - HALF]);
    float4 v = *src;
    unsigned short o[4];
    float vv[4] = {v.x, v.y, v.z, v.w};
    #pragma unroll
    for (int t = 0; t < 4; ++t) {
        unsigned int u = __float_as_uint(vv[t]);
        o[t] = (unsigned short)((u + 0x7fffu + ((u >> 16) & 1u)) >> 16);  // RNE
    }
    *reinterpret_cast<ushort4*>(&featsb[j]) = make_ushort4(o[0], o[1], o[2], o[3]);
}

// ---- kernel 2: posdot[i] = dot(f1_i, f2_i) / T  (f32, exact) ----
__global__ void pos_kernel(const float* __restrict__ f1,
                           const float* __restrict__ f2,
                           float* __restrict__ posdot) {
    int gt = blockIdx.x * blockDim.x + threadIdx.x;
    int row = gt >> 6;
    int lane = threadIdx.x & 63;
    float d = f1[row * DDIM + lane] * f2[row * DDIM + lane];
    #pragma unroll
    for (int m = 32; m; m >>= 1) d += __shfl_xor(d, m);
    if (lane == 0) posdot[row] = d * INV_T;
}

// ---- kernel 3: Ng[i] += sum_j(lab_j != lab_i) exp(dot_ij / T) ----
// 128x128 tile per block, 4 waves (2x2 of 64x64), MFMA 16x16x32 bf16,
// fragments loaded directly from global (operands are L1/L2 resident).
__global__ __launch_bounds__(256) void ng_kernel(const unsigned short* __restrict__ featsb,
                                                 const int* __restrict__ label,
                                                 float* __restrict__ Ng) {
    __shared__ int rlab[128];
    __shared__ int clab[128];
    const int tid = threadIdx.x;
    const int rowBase = blockIdx.y * 128;
    const int colBase = blockIdx.x * 128;
    if (tid < 128) rlab[tid] = label[(rowBase + tid) & (NROWS - 1)];
    else           clab[tid - 128] = label[(colBase + tid - 128) & (NROWS - 1)];
    __syncthreads();

    const int wid  = tid >> 6;
    const int lane = tid & 63;
    const int wr = (wid >> 1) * 64;   // wave row offset in tile
    const int wc = (wid & 1) * 64;    // wave col offset in tile
    const int lr = lane & 15;         // fragment row/col within 16
    const int lk = lane >> 4;         // k-octet group (0..3)

    f32x4 acc[4][4];
    f32x4 zero = {0.f, 0.f, 0.f, 0.f};
    #pragma unroll
    for (int m = 0; m < 4; ++m)
        #pragma unroll
        for (int n = 0; n < 4; ++n) acc[m][n] = zero;

    // feats row r: bytes r*128; fragment (r, koct): elements r*64 + koct*8
    #pragma unroll
    for (int kb = 0; kb < 2; ++kb) {     // K=64 -> two K=32 steps
        bf16x8 afr[4], bfr[4];
        #pragma unroll
        for (int m = 0; m < 4; ++m) {
            int r = rowBase + wr + m * 16 + lr;
            afr[m] = *reinterpret_cast<const bf16x8*>(&featsb[r * DDIM + lk * 8 + kb * 32]);
        }
        #pragma unroll
        for (int n = 0; n < 4; ++n) {
            int c = colBase + wc + n * 16 + lr;
            bfr[n] = *reinterpret_cast<const bf16x8*>(&featsb[c * DDIM + lk * 8 + kb * 32]);
        }
        #pragma unroll
        for (int m = 0; m < 4; ++m)
            #pragma unroll
            for (int n = 0; n < 4; ++n)
                acc[m][n] = __builtin_amdgcn_mfma_f32_16x16x32_bf16(afr[m], bfr[n], acc[m][n], 0, 0, 0);
    }

    // epilogue: exp, mask, row-sum
    const int rg = lane >> 4;           // C/D row group
    float rsum[4][4];
    #pragma unroll
    for (int m = 0; m < 4; ++m) {
        #pragma unroll
        for (int r = 0; r < 4; ++r) {
            int trow = wr + m * 16 + rg * 4 + r;     // row within tile
            int rl = rlab[trow];
            float s = 0.f;
            #pragma unroll
            for (int n = 0; n < 4; ++n) {
                int tcol = wc + n * 16 + lr;         // col within tile
                float e = __expf(acc[m][n][r] * INV_T);
                s += (clab[tcol] != rl) ? e : 0.f;
            }
            rsum[m][r] = s;
        }
    }
    // reduce across the 16-lane column group
    #pragma unroll
    for (int m = 0; m < 4; ++m) {
        #pragma unroll
        for (int r = 0; r < 4; ++r) {
            float v = rsum[m][r];
            v += __shfl_xor(v, 1);
            v += __shfl_xor(v, 2);
            v += __shfl_xor(v, 4);
            v += __shfl_xor(v, 8);
            rsum[m][r] = v;
        }
    }
    if (lr == 0) {
        #pragma unroll
        for (int m = 0; m < 4; ++m)
            #pragma unroll
            for (int r = 0; r < 4; ++r) {
                int grow = rowBase + wr + m * 16 + rg * 4 + r;
                atomicAdd(&Ng[grow], rsum[m][r]);
            }
    }
}

// ---- kernel 4: final loss ----
__global__ void final_kernel(const float* __restrict__ Ng,
                             const float* __restrict__ posdot,
                             const int* __restrict__ label,
                             float* __restrict__ out) {
    __shared__ int cnt[16];
    __shared__ float partial[4];
    int tid = threadIdx.x;
    if (tid < 16) cnt[tid] = 0;
    __syncthreads();
    for (int i = tid; i < NROWS; i += 256) atomicAdd(&cnt[label[i]], 1);
    __syncthreads();
    float s = 0.f;
    for (int i = tid; i < TWO_N; i += 256) {
        int base = i & (NROWS - 1);
        float pd = posdot[base];
        float gs = 2.0f * (float)cnt[label[base]];
        // -log(pos/(Ng+pos)) = log(Ng + exp(pd)) - pd
        s += (logf(Ng[i] + expf(pd)) - pd) / gs;
    }
    #pragma unroll
    for (int m = 32; m; m >>= 1) s += __shfl_xor(s, m);
    if ((tid & 63) == 0) partial[tid >> 6] = s;
    __syncthreads();
    if (tid == 0) out[0] = partial[0] + partial[1] + partial[2] + partial[3];
}

extern "C" void kernel_launch(void* const* d_in, const int* in_sizes, int n_in,
                              void* d_out, int out_size, void* d_ws, size_t ws_size,
                              hipStream_t stream) {
    const float* f1 = (const float*)d_in[0];
    const float* f2 = (const float*)d_in[1];
    const int* label = (const int*)d_in[2];
    float* out = (float*)d_out;

    char* ws = (char*)d_ws;
    unsigned short* featsb = (unsigned short*)ws;                       // 1 MB
    float* Ng     = (float*)(ws + (size_t)TWO_N * DDIM * 2);            // 32 KB
    float* posdot = (float*)(ws + (size_t)TWO_N * DDIM * 2 + TWO_N * 4); // 16 KB

    hipMemsetAsync(Ng, 0, TWO_N * sizeof(float), stream);
    convert_kernel<<<dim3(TWO_N * DDIM / 4 / 256), dim3(256), 0, stream>>>(f1, f2, featsb);
    pos_kernel<<<dim3(NROWS * 64 / 256), dim3(256), 0, stream>>>(f1, f2, posdot);
    ng_kernel<<<dim3(TWO_N / 128, TWO_N / 128), dim3(256), 0, stream>>>(featsb, label, Ng);
    final_kernel<<<dim3(1), dim3(256), 0, stream>>>(Ng, posdot, label, out);
}

// Round 3
// 109.715 us; speedup vs baseline: 1.4499x; 1.4499x over previous
//
#include <hip/hip_runtime.h>
#include <hip/hip_bf16.h>

#define NROWS 4096
#define TWO_N 8192
#define DDIM 64
#define INV_T 20.0f
#define CHUNKS 16
#define JTILES 4   // (TWO_N / CHUNKS) / 128

typedef short bf16x8 __attribute__((ext_vector_type(8)));
typedef float f32x4 __attribute__((ext_vector_type(4)));

__device__ __forceinline__ unsigned short f32_to_bf16_rne(float f) {
    unsigned int u = __float_as_uint(f);
    return (unsigned short)((u + 0x7fffu + ((u >> 16) & 1u)) >> 16);
}

// ---- kernel 1: fused convert (f32 -> bf16 feats) + posdot ----
// 256 blocks x 256 threads; thread t handles 4 consecutive elems (float4).
// 16 consecutive threads cover one row of 64.
__global__ void prep_kernel(const float* __restrict__ f1,
                            const float* __restrict__ f2,
                            unsigned short* __restrict__ featsb,
                            float* __restrict__ posdot) {
    int t = blockIdx.x * blockDim.x + threadIdx.x;
    int j = t * 4;
    float4 a = *reinterpret_cast<const float4*>(&f1[j]);
    float4 b = *reinterpret_cast<const float4*>(&f2[j]);
    ushort4 ua = make_ushort4(f32_to_bf16_rne(a.x), f32_to_bf16_rne(a.y),
                              f32_to_bf16_rne(a.z), f32_to_bf16_rne(a.w));
    ushort4 ub = make_ushort4(f32_to_bf16_rne(b.x), f32_to_bf16_rne(b.y),
                              f32_to_bf16_rne(b.z), f32_to_bf16_rne(b.w));
    *reinterpret_cast<ushort4*>(&featsb[j]) = ua;
    *reinterpret_cast<ushort4*>(&featsb[NROWS * DDIM + j]) = ub;
    float d = a.x * b.x + a.y * b.y + a.z * b.z + a.w * b.w;
    d += __shfl_xor(d, 1);
    d += __shfl_xor(d, 2);
    d += __shfl_xor(d, 4);
    d += __shfl_xor(d, 8);
    if ((threadIdx.x & 15) == 0) posdot[j >> 6] = d * INV_T;
}

// ---- kernel 2: NgPart[chunk][row] = sum over chunk cols (lab_c != lab_r) exp(dot/T) ----
// Block: 128-row panel x 512-col chunk. 4 waves in 2x2 (64x64 each).
// A-fragments register-resident across the 4 column tiles. No atomics.
__global__ __launch_bounds__(256, 2) void ng_kernel(const unsigned short* __restrict__ featsb,
                                                    const int* __restrict__ label,
                                                    float* __restrict__ NgPart) {
    __shared__ int clabS[512];
    __shared__ float rowred[128];
    const int tid = threadIdx.x;
    const int rowBase = blockIdx.y * 128;
    const int chunk = blockIdx.x;
    const int colBase0 = chunk * 512;
    for (int i = tid; i < 512; i += 256)
        clabS[i] = label[(colBase0 + i) & (NROWS - 1)];
    __syncthreads();

    const int wid = tid >> 6;
    const int lane = tid & 63;
    const int wr = (wid >> 1) * 64;
    const int wc = (wid & 1) * 64;
    const int lr = lane & 15;
    const int lk = lane >> 4;

    // A fragments: resident for the whole block
    bf16x8 afr[2][4];
    #pragma unroll
    for (int kb = 0; kb < 2; ++kb)
        #pragma unroll
        for (int m = 0; m < 4; ++m) {
            int r = rowBase + wr + m * 16 + lr;
            afr[kb][m] = *reinterpret_cast<const bf16x8*>(&featsb[r * DDIM + lk * 8 + kb * 32]);
        }

    // row labels for this thread's C rows (fixed for whole block)
    int rl[4][4];
    #pragma unroll
    for (int m = 0; m < 4; ++m)
        #pragma unroll
        for (int r = 0; r < 4; ++r)
            rl[m][r] = label[(rowBase + wr + m * 16 + lk * 4 + r) & (NROWS - 1)];

    float rsum[4][4];
    #pragma unroll
    for (int m = 0; m < 4; ++m)
        #pragma unroll
        for (int r = 0; r < 4; ++r) rsum[m][r] = 0.f;

    #pragma unroll
    for (int jt = 0; jt < JTILES; ++jt) {
        const int colLoc = wc + jt * 128;              // index into clabS
        f32x4 acc[4][4];
        f32x4 zero = {0.f, 0.f, 0.f, 0.f};
        #pragma unroll
        for (int m = 0; m < 4; ++m)
            #pragma unroll
            for (int n = 0; n < 4; ++n) acc[m][n] = zero;

        #pragma unroll
        for (int kb = 0; kb < 2; ++kb) {
            bf16x8 bfr[4];
            #pragma unroll
            for (int n = 0; n < 4; ++n) {
                int c = colBase0 + colLoc + n * 16 + lr;
                bfr[n] = *reinterpret_cast<const bf16x8*>(&featsb[c * DDIM + lk * 8 + kb * 32]);
            }
            #pragma unroll
            for (int m = 0; m < 4; ++m)
                #pragma unroll
                for (int n = 0; n < 4; ++n)
                    acc[m][n] = __builtin_amdgcn_mfma_f32_16x16x32_bf16(afr[kb][m], bfr[n], acc[m][n], 0, 0, 0);
        }

        int cl[4];
        #pragma unroll
        for (int n = 0; n < 4; ++n) cl[n] = clabS[colLoc + n * 16 + lr];

        #pragma unroll
        for (int m = 0; m < 4; ++m)
            #pragma unroll
            for (int r = 0; r < 4; ++r) {
                int lab = rl[m][r];
                float s = 0.f;
                #pragma unroll
                for (int n = 0; n < 4; ++n) {
                    float e = __expf(acc[m][n][r] * INV_T);
                    s += (cl[n] != lab) ? e : 0.f;
                }
                rsum[m][r] += s;
            }
    }

    // reduce across the 16-lane column group
    #pragma unroll
    for (int m = 0; m < 4; ++m)
        #pragma unroll
        for (int r = 0; r < 4; ++r) {
            float v = rsum[m][r];
            v += __shfl_xor(v, 1);
            v += __shfl_xor(v, 2);
            v += __shfl_xor(v, 4);
            v += __shfl_xor(v, 8);
            rsum[m][r] = v;
        }

    // combine the two waves sharing the same rows (wc=0 and wc=64)
    if (wc == 64 && lr == 0) {
        #pragma unroll
        for (int m = 0; m < 4; ++m)
            #pragma unroll
            for (int r = 0; r < 4; ++r)
                rowred[wr + m * 16 + lk * 4 + r] = rsum[m][r];
    }
    __syncthreads();
    if (wc == 0 && lr == 0) {
        #pragma unroll
        for (int m = 0; m < 4; ++m)
            #pragma unroll
            for (int r = 0; r < 4; ++r) {
                int idx = wr + m * 16 + lk * 4 + r;
                NgPart[chunk * TWO_N + rowBase + idx] = rsum[m][r] + rowred[idx];
            }
    }
}

// ---- kernel 3: final loss ----
__global__ void final_kernel(const float* __restrict__ NgPart,
                             const float* __restrict__ posdot,
                             const int* __restrict__ label,
                             float* __restrict__ out) {
    __shared__ int cnt[16];
    __shared__ float red[16];
    int tid = threadIdx.x;  // 1024 threads
    if (tid < 16) cnt[tid] = 0;
    __syncthreads();
    for (int i = tid; i < NROWS; i += 1024) atomicAdd(&cnt[label[i]], 1);
    __syncthreads();
    float s = 0.f;
    for (int i = tid; i < TWO_N; i += 1024) {
        float ng = 0.f;
        #pragma unroll
        for (int c = 0; c < CHUNKS; ++c) ng += NgPart[c * TWO_N + i];
        int base = i & (NROWS - 1);
        float pd = posdot[base];
        float gs = 2.0f * (float)cnt[label[base]];
        s += (__logf(ng + __expf(pd)) - pd) / gs;
    }
    #pragma unroll
    for (int m = 32; m; m >>= 1) s += __shfl_xor(s, m);
    if ((tid & 63) == 0) red[tid >> 6] = s;
    __syncthreads();
    if (tid == 0) {
        float t = 0.f;
        #pragma unroll
        for (int i = 0; i < 16; ++i) t += red[i];
        out[0] = t;
    }
}

extern "C" void kernel_launch(void* const* d_in, const int* in_sizes, int n_in,
                              void* d_out, int out_size, void* d_ws, size_t ws_size,
                              hipStream_t stream) {
    const float* f1 = (const float*)d_in[0];
    const float* f2 = (const float*)d_in[1];
    const int* label = (const int*)d_in[2];
    float* out = (float*)d_out;

    char* ws = (char*)d_ws;
    unsigned short* featsb = (unsigned short*)ws;                          // 1 MB
    float* NgPart = (float*)(ws + (size_t)TWO_N * DDIM * 2);               // 512 KB
    float* posdot = (float*)(ws + (size_t)TWO_N * DDIM * 2 + (size_t)CHUNKS * TWO_N * 4);  // 16 KB

    prep_kernel<<<dim3(NROWS * DDIM / 4 / 256), dim3(256), 0, stream>>>(f1, f2, featsb, posdot);
    ng_kernel<<<dim3(CHUNKS, TWO_N / 128), dim3(256), 0, stream>>>(featsb, label, NgPart);
    final_kernel<<<dim3(1), dim3(1024), 0, stream>>>(NgPart, posdot, label, out);
}

// Round 5
// 95.755 us; speedup vs baseline: 1.6613x; 1.1458x over previous
//
#include <hip/hip_runtime.h>
#include <hip/hip_bf16.h>

#define NROWS 4096
#define TWO_N 8192
#define DDIM 64
#define INV_T 20.0f
#define CHUNK 512      // columns per block
#define JT 8           // 64-col steps per chunk

typedef short bf16x8 __attribute__((ext_vector_type(8)));
typedef float f32x4 __attribute__((ext_vector_type(4)));

__device__ __forceinline__ unsigned short f32_to_bf16_rne(float f) {
    unsigned int u = __float_as_uint(f);
    return (unsigned short)((u + 0x7fffu + ((u >> 16) & 1u)) >> 16);
}

// ---- kernel 1: fused convert (f32 -> bf16 feats) + posdot + zero-init of Ng/out ----
// 256 blocks x 256 threads; thread t handles one float4 of f1 AND f2.
__global__ void prep_kernel(const float* __restrict__ f1,
                            const float* __restrict__ f2,
                            unsigned short* __restrict__ featsb,
                            float* __restrict__ posdot,
                            float* __restrict__ Ng,
                            float* __restrict__ out) {
    // zero Ng (8192 floats) and out (1 float); ng/final are stream-ordered after us
    if (blockIdx.x < 8) {
        float4 z = make_float4(0.f, 0.f, 0.f, 0.f);
        reinterpret_cast<float4*>(Ng)[blockIdx.x * 256 + threadIdx.x] = z;
        if (blockIdx.x == 0 && threadIdx.x == 0) out[0] = 0.f;
    }
    int t = blockIdx.x * blockDim.x + threadIdx.x;
    int j = t * 4;
    float4 a = *reinterpret_cast<const float4*>(&f1[j]);
    float4 b = *reinterpret_cast<const float4*>(&f2[j]);
    ushort4 ua = make_ushort4(f32_to_bf16_rne(a.x), f32_to_bf16_rne(a.y),
                              f32_to_bf16_rne(a.z), f32_to_bf16_rne(a.w));
    ushort4 ub = make_ushort4(f32_to_bf16_rne(b.x), f32_to_bf16_rne(b.y),
                              f32_to_bf16_rne(b.z), f32_to_bf16_rne(b.w));
    *reinterpret_cast<ushort4*>(&featsb[j]) = ua;
    *reinterpret_cast<ushort4*>(&featsb[NROWS * DDIM + j]) = ub;
    float d = a.x * b.x + a.y * b.y + a.z * b.z + a.w * b.w;
    d += __shfl_xor(d, 1);
    d += __shfl_xor(d, 2);
    d += __shfl_xor(d, 4);
    d += __shfl_xor(d, 8);
    if ((threadIdx.x & 15) == 0) posdot[j >> 6] = d * INV_T;
}

// ---- kernel 2: Ng[i] += sum_{j in chunk, lab_j != lab_i} exp(dot_ij / T) ----
// Block: 128 rows x 512-col chunk. 4 waves, each owning 32 rows (disjoint).
// Per jt step a wave computes 32x64 via acc[2][4]; ~100 VGPRs -> no spill.
__global__ __launch_bounds__(256, 2) void ng_kernel(const unsigned short* __restrict__ featsb,
                                                    const int* __restrict__ label,
                                                    float* __restrict__ Ng) {
    __shared__ int clabS[CHUNK];
    __shared__ int rlabS[128];
    const int tid = threadIdx.x;
    const int rowBase = blockIdx.y * 128;
    const int colBase = blockIdx.x * CHUNK;
    for (int i = tid; i < CHUNK; i += 256)
        clabS[i] = label[(colBase + i) & (NROWS - 1)];
    if (tid < 128) rlabS[tid] = label[(rowBase + tid) & (NROWS - 1)];
    __syncthreads();

    const int wid = tid >> 6;
    const int lane = tid & 63;
    const int lr = lane & 15;
    const int lk = lane >> 4;
    const int wr = wid * 32;          // this wave's 32-row slice

    // A fragments: resident for the whole block (16 VGPR)
    bf16x8 afr[2][2];
    #pragma unroll
    for (int kb = 0; kb < 2; ++kb)
        #pragma unroll
        for (int m = 0; m < 2; ++m) {
            int r = rowBase + wr + m * 16 + lr;
            afr[kb][m] = *reinterpret_cast<const bf16x8*>(&featsb[r * DDIM + lk * 8 + kb * 32]);
        }

    // labels of this thread's 8 accumulator rows
    int rl[2][4];
    #pragma unroll
    for (int m = 0; m < 2; ++m)
        #pragma unroll
        for (int r = 0; r < 4; ++r)
            rl[m][r] = rlabS[wr + m * 16 + lk * 4 + r];

    float rsum[2][4];
    #pragma unroll
    for (int m = 0; m < 2; ++m)
        #pragma unroll
        for (int r = 0; r < 4; ++r) rsum[m][r] = 0.f;

    for (int jt = 0; jt < JT; ++jt) {
        const int c0 = jt * 64;
        f32x4 acc[2][4];
        f32x4 zero = {0.f, 0.f, 0.f, 0.f};
        #pragma unroll
        for (int m = 0; m < 2; ++m)
            #pragma unroll
            for (int n = 0; n < 4; ++n) acc[m][n] = zero;

        #pragma unroll
        for (int kb = 0; kb < 2; ++kb) {
            bf16x8 bfr[4];
            #pragma unroll
            for (int n = 0; n < 4; ++n) {
                int c = colBase + c0 + n * 16 + lr;
                bfr[n] = *reinterpret_cast<const bf16x8*>(&featsb[c * DDIM + lk * 8 + kb * 32]);
            }
            #pragma unroll
            for (int m = 0; m < 2; ++m)
                #pragma unroll
                for (int n = 0; n < 4; ++n)
                    acc[m][n] = __builtin_amdgcn_mfma_f32_16x16x32_bf16(afr[kb][m], bfr[n], acc[m][n], 0, 0, 0);
        }

        int cl[4];
        #pragma unroll
        for (int n = 0; n < 4; ++n) cl[n] = clabS[c0 + n * 16 + lr];

        #pragma unroll
        for (int m = 0; m < 2; ++m)
            #pragma unroll
            for (int r = 0; r < 4; ++r) {
                int lab = rl[m][r];
                float s = 0.f;
                #pragma unroll
                for (int n = 0; n < 4; ++n) {
                    float e = __expf(acc[m][n][r] * INV_T);
                    s += (cl[n] != lab) ? e : 0.f;
                }
                rsum[m][r] += s;
            }
    }

    // reduce across the 16 lanes of each column group, then one atomic per row
    #pragma unroll
    for (int m = 0; m < 2; ++m)
        #pragma unroll
        for (int r = 0; r < 4; ++r) {
            float v = rsum[m][r];
            v += __shfl_xor(v, 1);
            v += __shfl_xor(v, 2);
            v += __shfl_xor(v, 4);
            v += __shfl_xor(v, 8);
            rsum[m][r] = v;
        }
    if (lr == 0) {
        #pragma unroll
        for (int m = 0; m < 2; ++m)
            #pragma unroll
            for (int r = 0; r < 4; ++r)
                atomicAdd(&Ng[rowBase + wr + m * 16 + lk * 4 + r], rsum[m][r]);
    }
}

// ---- kernel 3: final loss (16 blocks x 256 threads, atomic partial sums) ----
__global__ void final_kernel(const float* __restrict__ Ng,
                             const float* __restrict__ posdot,
                             const int* __restrict__ label,
                             float* __restrict__ out) {
    __shared__ int cnt[16];
    __shared__ float red[4];
    int tid = threadIdx.x;
    if (tid < 16) cnt[tid] = 0;
    __syncthreads();
    for (int i = tid; i < NROWS; i += 256) atomicAdd(&cnt[label[i]], 1);
    __syncthreads();
    float s = 0.f;
    #pragma unroll
    for (int k = 0; k < 2; ++k) {
        int i = blockIdx.x * 512 + k * 256 + tid;
        int base = i & (NROWS - 1);
        float pd = posdot[base];
        float gs = 2.0f * (float)cnt[label[base]];
        s += (__logf(Ng[i] + __expf(pd)) - pd) / gs;
    }
    #pragma unroll
    for (int m = 32; m; m >>= 1) s += __shfl_xor(s, m);
    if ((tid & 63) == 0) red[tid >> 6] = s;
    __syncthreads();
    if (tid == 0) atomicAdd(out, red[0] + red[1] + red[2] + red[3]);
}

extern "C" void kernel_launch(void* const* d_in, const int* in_sizes, int n_in,
                              void* d_out, int out_size, void* d_ws, size_t ws_size,
                              hipStream_t stream) {
    const float* f1 = (const float*)d_in[0];
    const float* f2 = (const float*)d_in[1];
    const int* label = (const int*)d_in[2];
    float* out = (float*)d_out;

    char* ws = (char*)d_ws;
    unsigned short* featsb = (unsigned short*)ws;                 // 1 MB
    float* Ng     = (float*)(ws + (size_t)TWO_N * DDIM * 2);      // 32 KB
    float* posdot = (float*)(ws + (size_t)TWO_N * DDIM * 2 + TWO_N * 4);  // 16 KB

    prep_kernel<<<dim3(NROWS * DDIM / 4 / 256), dim3(256), 0, stream>>>(f1, f2, featsb, posdot, Ng, out);
    ng_kernel<<<dim3(TWO_N / CHUNK, TWO_N / 128), dim3(256), 0, stream>>>(featsb, label, Ng);
    final_kernel<<<dim3(TWO_N / 512), dim3(256), 0, stream>>>(Ng, posdot, label, out);
}

// Round 6
// 84.112 us; speedup vs baseline: 1.8913x; 1.1384x over previous
//
#include <hip/hip_runtime.h>
#include <hip/hip_bf16.h>

#define NROWS 4096
#define TWO_N 8192
#define DDIM 64
#define INV_T 20.0f
#define CHUNK 512      // columns per ng block
#define JT 8           // 64-col steps per chunk

typedef short bf16x8 __attribute__((ext_vector_type(8)));
typedef float f32x4 __attribute__((ext_vector_type(4)));

__device__ __forceinline__ unsigned short f32_to_bf16_rne(float f) {
    unsigned int u = __float_as_uint(f);
    return (unsigned short)((u + 0x7fffu + ((u >> 16) & 1u)) >> 16);
}

// featsT fragment-major layout: element (row=16g+lr, col=kb*32+lk*8+e) lives at
//   featsT[g*1024 + kb*512 + (lk*16+lr)*8 + e]
// so an MFMA fragment load for (row-group g, kb) is featsT + g*1024 + kb*512 + lane*8
// -> lane-contiguous, one coalesced 1KB transaction per wave.

// ---- kernel 1: convert f32 -> bf16 fragment-major + posdot + zero Ng/out ----
// thread t: row r = t>>4, quad q = t&15 (cols 4q..4q+3), for both f1 and f2.
__global__ void prep_kernel(const float* __restrict__ f1,
                            const float* __restrict__ f2,
                            unsigned short* __restrict__ featsT,
                            float* __restrict__ posdot,
                            float* __restrict__ Ng,
                            float* __restrict__ out) {
    if (blockIdx.x < 8) {
        float4 z = make_float4(0.f, 0.f, 0.f, 0.f);
        reinterpret_cast<float4*>(Ng)[blockIdx.x * 256 + threadIdx.x] = z;
        if (blockIdx.x == 0 && threadIdx.x == 0) out[0] = 0.f;
    }
    int t = blockIdx.x * blockDim.x + threadIdx.x;
    int r = t >> 4;
    int q = t & 15;
    int j = r * DDIM + q * 4;
    float4 a = *reinterpret_cast<const float4*>(&f1[j]);
    float4 b = *reinterpret_cast<const float4*>(&f2[j]);
    ushort4 ua = make_ushort4(f32_to_bf16_rne(a.x), f32_to_bf16_rne(a.y),
                              f32_to_bf16_rne(a.z), f32_to_bf16_rne(a.w));
    ushort4 ub = make_ushort4(f32_to_bf16_rne(b.x), f32_to_bf16_rne(b.y),
                              f32_to_bf16_rne(b.z), f32_to_bf16_rne(b.w));
    // fragment-major destination
    int g1 = r >> 4;
    int lr = r & 15;
    int kb = q >> 3;
    int lk = (q & 7) >> 1;
    int e  = (q & 1) * 4;
    int off = g1 * 1024 + kb * 512 + (lk * 16 + lr) * 8 + e;
    *reinterpret_cast<ushort4*>(&featsT[off]) = ua;                 // f1 half: groups 0..255
    *reinterpret_cast<ushort4*>(&featsT[off + 256 * 1024]) = ub;    // f2 half: groups 256..511
    // posdot (16 threads per row, aligned 16-lane subgroup)
    float d = a.x * b.x + a.y * b.y + a.z * b.z + a.w * b.w;
    d += __shfl_xor(d, 1);
    d += __shfl_xor(d, 2);
    d += __shfl_xor(d, 4);
    d += __shfl_xor(d, 8);
    if (q == 0) posdot[r] = d * INV_T;
}

// ---- kernel 2: Ng[i] += sum_{j in chunk, lab_j != lab_i} exp(dot_ij / T) ----
// Block: 128 rows x 512-col chunk, 4 waves each owning a disjoint 32-row slice.
// All fragment loads lane-contiguous from featsT. ~110 VGPR, 4 blocks/CU.
__global__ __launch_bounds__(256, 4) void ng_kernel(const unsigned short* __restrict__ featsT,
                                                    const int* __restrict__ label,
                                                    float* __restrict__ Ng) {
    __shared__ int clabS[CHUNK];
    __shared__ int rlabS[128];
    const int tid = threadIdx.x;
    const int rowBase = blockIdx.y * 128;
    const int colBase = blockIdx.x * CHUNK;
    for (int i = tid; i < CHUNK; i += 256)
        clabS[i] = label[(colBase + i) & (NROWS - 1)];
    if (tid < 128) rlabS[tid] = label[(rowBase + tid) & (NROWS - 1)];
    __syncthreads();

    const int wid = tid >> 6;
    const int lane = tid & 63;
    const int lr = lane & 15;
    const int lk = lane >> 4;
    const int wr = wid * 32;                 // this wave's 32-row slice
    const int gr0 = (rowBase + wr) >> 4;     // row-group index base (m adds 1)
    const int gc0 = colBase >> 4;            // col-group index base

    // A fragments: resident for the whole block, coalesced loads
    bf16x8 afr[2][2];
    #pragma unroll
    for (int kb = 0; kb < 2; ++kb)
        #pragma unroll
        for (int m = 0; m < 2; ++m)
            afr[kb][m] = *reinterpret_cast<const bf16x8*>(
                &featsT[(gr0 + m) * 1024 + kb * 512 + lane * 8]);

    // labels of this thread's 8 accumulator rows
    int rl[2][4];
    #pragma unroll
    for (int m = 0; m < 2; ++m)
        #pragma unroll
        for (int r = 0; r < 4; ++r)
            rl[m][r] = rlabS[wr + m * 16 + lk * 4 + r];

    float rsum[2][4];
    #pragma unroll
    for (int m = 0; m < 2; ++m)
        #pragma unroll
        for (int r = 0; r < 4; ++r) rsum[m][r] = 0.f;

    for (int jt = 0; jt < JT; ++jt) {
        f32x4 acc[2][4];
        f32x4 zero = {0.f, 0.f, 0.f, 0.f};
        #pragma unroll
        for (int m = 0; m < 2; ++m)
            #pragma unroll
            for (int n = 0; n < 4; ++n) acc[m][n] = zero;

        #pragma unroll
        for (int kb = 0; kb < 2; ++kb) {
            bf16x8 bfr[4];
            #pragma unroll
            for (int n = 0; n < 4; ++n)
                bfr[n] = *reinterpret_cast<const bf16x8*>(
                    &featsT[(gc0 + jt * 4 + n) * 1024 + kb * 512 + lane * 8]);
            #pragma unroll
            for (int m = 0; m < 2; ++m)
                #pragma unroll
                for (int n = 0; n < 4; ++n)
                    acc[m][n] = __builtin_amdgcn_mfma_f32_16x16x32_bf16(afr[kb][m], bfr[n], acc[m][n], 0, 0, 0);
        }

        int cl[4];
        #pragma unroll
        for (int n = 0; n < 4; ++n) cl[n] = clabS[jt * 64 + n * 16 + lr];

        #pragma unroll
        for (int m = 0; m < 2; ++m)
            #pragma unroll
            for (int r = 0; r < 4; ++r) {
                int lab = rl[m][r];
                float s = 0.f;
                #pragma unroll
                for (int n = 0; n < 4; ++n) {
                    float e = __expf(acc[m][n][r] * INV_T);
                    s += (cl[n] != lab) ? e : 0.f;
                }
                rsum[m][r] += s;
            }
    }

    // reduce across the 16 lanes of each column group, then one atomic per row
    #pragma unroll
    for (int m = 0; m < 2; ++m)
        #pragma unroll
        for (int r = 0; r < 4; ++r) {
            float v = rsum[m][r];
            v += __shfl_xor(v, 1);
            v += __shfl_xor(v, 2);
            v += __shfl_xor(v, 4);
            v += __shfl_xor(v, 8);
            rsum[m][r] = v;
        }
    if (lr == 0) {
        #pragma unroll
        for (int m = 0; m < 2; ++m)
            #pragma unroll
            for (int r = 0; r < 4; ++r)
                atomicAdd(&Ng[rowBase + wr + m * 16 + lk * 4 + r], rsum[m][r]);
    }
}

// ---- kernel 3: final loss (16 blocks x 256 threads, atomic partial sums) ----
__global__ void final_kernel(const float* __restrict__ Ng,
                             const float* __restrict__ posdot,
                             const int* __restrict__ label,
                             float* __restrict__ out) {
    __shared__ int cnt[16];
    __shared__ float red[4];
    int tid = threadIdx.x;
    if (tid < 16) cnt[tid] = 0;
    __syncthreads();
    for (int i = tid; i < NROWS; i += 256) atomicAdd(&cnt[label[i]], 1);
    __syncthreads();
    float s = 0.f;
    #pragma unroll
    for (int k = 0; k < 2; ++k) {
        int i = blockIdx.x * 512 + k * 256 + tid;
        int base = i & (NROWS - 1);
        float pd = posdot[base];
        float gs = 2.0f * (float)cnt[label[base]];
        s += (__logf(Ng[i] + __expf(pd)) - pd) / gs;
    }
    #pragma unroll
    for (int m = 32; m; m >>= 1) s += __shfl_xor(s, m);
    if ((tid & 63) == 0) red[tid >> 6] = s;
    __syncthreads();
    if (tid == 0) atomicAdd(out, red[0] + red[1] + red[2] + red[3]);
}

extern "C" void kernel_launch(void* const* d_in, const int* in_sizes, int n_in,
                              void* d_out, int out_size, void* d_ws, size_t ws_size,
                              hipStream_t stream) {
    const float* f1 = (const float*)d_in[0];
    const float* f2 = (const float*)d_in[1];
    const int* label = (const int*)d_in[2];
    float* out = (float*)d_out;

    char* ws = (char*)d_ws;
    unsigned short* featsT = (unsigned short*)ws;                 // 1 MB
    float* Ng     = (float*)(ws + (size_t)TWO_N * DDIM * 2);      // 32 KB
    float* posdot = (float*)(ws + (size_t)TWO_N * DDIM * 2 + TWO_N * 4);  // 16 KB

    prep_kernel<<<dim3(NROWS * DDIM / 4 / 256), dim3(256), 0, stream>>>(f1, f2, featsT, posdot, Ng, out);
    ng_kernel<<<dim3(TWO_N / CHUNK, TWO_N / 128), dim3(256), 0, stream>>>(featsT, label, Ng);
    final_kernel<<<dim3(TWO_N / 512), dim3(256), 0, stream>>>(Ng, posdot, label, out);
}